// Round 1
// baseline (619.614 us; speedup 1.0000x reference)
//
#include <hip/hip_runtime.h>

#define FEAT 128
#define NGRAPH 512
#define NCLS 16

// ---------------- CSR build ----------------

__global__ void k_hist(const int* __restrict__ col, int* __restrict__ hist, int E) {
    int i = blockIdx.x * blockDim.x + threadIdx.x;
    if (i < E) atomicAdd(&hist[col[i]], 1);
}

__global__ void k_dinv(const int* __restrict__ hist, float* __restrict__ dinv, int N) {
    int i = blockIdx.x * blockDim.x + threadIdx.x;
    if (i < N) dinv[i] = rsqrtf((float)(hist[i] + 1));   // +1 self loop, always > 0
}

// scan stage A: per-256-chunk sums
__global__ void k_scanA(const int* __restrict__ hist, int* __restrict__ partial, int N) {
    __shared__ int s[256];
    int i = blockIdx.x * 256 + threadIdx.x;
    s[threadIdx.x] = (i < N) ? hist[i] : 0;
    __syncthreads();
    for (int off = 128; off > 0; off >>= 1) {
        if (threadIdx.x < off) s[threadIdx.x] += s[threadIdx.x + off];
        __syncthreads();
    }
    if (threadIdx.x == 0) partial[blockIdx.x] = s[0];
}

// scan stage B: exclusive scan of partials (nb <= 256), single block
__global__ void k_scanB(int* __restrict__ partial, int nb) {
    __shared__ int s[256];
    int t = threadIdx.x;
    int orig = (t < nb) ? partial[t] : 0;
    s[t] = orig;
    __syncthreads();
    for (int off = 1; off < 256; off <<= 1) {
        int v = (t >= off) ? s[t - off] : 0;
        __syncthreads();
        s[t] += v;
        __syncthreads();
    }
    if (t < nb) partial[t] = s[t] - orig;   // exclusive
}

// scan stage C: per-chunk exclusive scan + chunk offset -> start, cur
__global__ void k_scanC(const int* __restrict__ hist, const int* __restrict__ partial,
                        int* __restrict__ start, int* __restrict__ cur, int N) {
    __shared__ int s[256];
    int t = threadIdx.x;
    int i = blockIdx.x * 256 + t;
    int orig = (i < N) ? hist[i] : 0;
    s[t] = orig;
    __syncthreads();
    for (int off = 1; off < 256; off <<= 1) {
        int v = (t >= off) ? s[t - off] : 0;
        __syncthreads();
        s[t] += v;
        __syncthreads();
    }
    if (i < N) {
        int ex = s[t] - orig + partial[blockIdx.x];
        start[i] = ex;
        cur[i] = ex;
    }
}

__global__ void k_fill(const int* __restrict__ row, const int* __restrict__ col,
                       const float* __restrict__ dinv, int* __restrict__ cur,
                       int* __restrict__ csr_row, float* __restrict__ csr_w, int E) {
    int i = blockIdx.x * blockDim.x + threadIdx.x;
    if (i >= E) return;
    int r = row[i], c = col[i];
    int pos = atomicAdd(&cur[c], 1);
    csr_row[pos] = r;
    csr_w[pos] = dinv[r] * dinv[c];
}

// ---------------- dense transform: C[M,128] = A[M,128] @ W[128,128] ----------------

#define BM 64
#define BK 32

__global__ __launch_bounds__(256) void k_gemm(const float* __restrict__ A,
                                              const float* __restrict__ W,
                                              float* __restrict__ C, int M) {
    __shared__ float As[BM][BK + 1];       // stride 33 -> conflict-light scalar reads
    __shared__ float Ws[BK][FEAT + 4];     // stride 132, keeps 16B alignment for float4
    int tid = threadIdx.x;
    int m0 = blockIdx.x * BM;
    int ty = tid >> 4, tx = tid & 15;      // 16x16 thread grid; thread: 4 rows x 8 cols
    float acc[4][8] = {};

    for (int kt = 0; kt < FEAT; kt += BK) {
        // A tile: 64 x 32  (512 float4)
        for (int u = tid; u < BM * BK / 4; u += 256) {
            int ar = u >> 3, ac = (u & 7) * 4;
            int gr = m0 + ar;
            float4 v = make_float4(0.f, 0.f, 0.f, 0.f);
            if (gr < M) v = *(const float4*)&A[(size_t)gr * FEAT + kt + ac];
            As[ar][ac + 0] = v.x; As[ar][ac + 1] = v.y;
            As[ar][ac + 2] = v.z; As[ar][ac + 3] = v.w;
        }
        // W tile: 32 x 128 (1024 float4)
        for (int u = tid; u < BK * FEAT / 4; u += 256) {
            int wr = u >> 5, wc = (u & 31) * 4;
            float4 v = *(const float4*)&W[(size_t)(kt + wr) * FEAT + wc];
            Ws[wr][wc + 0] = v.x; Ws[wr][wc + 1] = v.y;
            Ws[wr][wc + 2] = v.z; Ws[wr][wc + 3] = v.w;
        }
        __syncthreads();
        #pragma unroll
        for (int kk = 0; kk < BK; ++kk) {
            float a0 = As[ty * 4 + 0][kk];
            float a1 = As[ty * 4 + 1][kk];
            float a2 = As[ty * 4 + 2][kk];
            float a3 = As[ty * 4 + 3][kk];
            float b[8];
            *(float4*)&b[0] = *(float4*)&Ws[kk][tx * 8];
            *(float4*)&b[4] = *(float4*)&Ws[kk][tx * 8 + 4];
            #pragma unroll
            for (int j = 0; j < 8; ++j) {
                acc[0][j] = fmaf(a0, b[j], acc[0][j]);
                acc[1][j] = fmaf(a1, b[j], acc[1][j]);
                acc[2][j] = fmaf(a2, b[j], acc[2][j]);
                acc[3][j] = fmaf(a3, b[j], acc[3][j]);
            }
        }
        __syncthreads();
    }
    #pragma unroll
    for (int i = 0; i < 4; ++i) {
        int gr = m0 + ty * 4 + i;
        if (gr < M) {
            *(float4*)&C[(size_t)gr * FEAT + tx * 8]     = make_float4(acc[i][0], acc[i][1], acc[i][2], acc[i][3]);
            *(float4*)&C[(size_t)gr * FEAT + tx * 8 + 4] = make_float4(acc[i][4], acc[i][5], acc[i][6], acc[i][7]);
        }
    }
}

// ---------------- aggregation: h[v] = sum_{e: col=v} t[row_e]*w_e + t[v]*dinv[v]^2 + b ----------------

__global__ __launch_bounds__(128) void k_agg(const float* __restrict__ t,
                                             const int* __restrict__ csr_row,
                                             const float* __restrict__ csr_w,
                                             const int* __restrict__ start,
                                             const int* __restrict__ endp,
                                             const float* __restrict__ dinv,
                                             const float* __restrict__ bias,
                                             float* __restrict__ h, int N, int do_relu) {
    int v = blockIdx.x;
    if (v >= N) return;
    int j = threadIdx.x;
    float dv = dinv[v];
    float acc = t[(size_t)v * FEAT + j] * dv * dv;     // self loop
    int s = start[v], e = endp[v];
    for (int p = s; p < e; ++p) {
        int r = csr_row[p];
        float w = csr_w[p];
        acc = fmaf(t[(size_t)r * FEAT + j], w, acc);
    }
    acc += bias[j];
    if (do_relu) acc = fmaxf(acc, 0.f);
    h[(size_t)v * FEAT + j] = acc;
}

// ---------------- pooling + classifier ----------------

__global__ void k_pool(const float* __restrict__ h, const int* __restrict__ batch,
                       float* __restrict__ pooled, int N) {
    int idx = blockIdx.x * blockDim.x + threadIdx.x;
    if (idx >= N * FEAT) return;
    int v = idx >> 7, j = idx & 127;
    atomicAdd(&pooled[batch[v] * FEAT + j], h[idx]);
}

__global__ void k_cnt(const int* __restrict__ batch, float* __restrict__ cntf, int N) {
    int v = blockIdx.x * blockDim.x + threadIdx.x;
    if (v < N) atomicAdd(&cntf[batch[v]], 1.0f);
}

__global__ void k_final(const float* __restrict__ pooled, const float* __restrict__ cntf,
                        const float* __restrict__ linW, const float* __restrict__ linb,
                        float* __restrict__ out) {
    int idx = blockIdx.x * blockDim.x + threadIdx.x;
    if (idx >= NGRAPH * NCLS) return;
    int g = idx >> 4, c = idx & 15;
    float inv = 1.0f / fmaxf(cntf[g], 1.0f);
    float acc = 0.f;
    #pragma unroll 8
    for (int jj = 0; jj < FEAT; ++jj)
        acc = fmaf(pooled[g * FEAT + jj], linW[jj * NCLS + c], acc);
    out[idx] = acc * inv + linb[c];
}

// ---------------- launch ----------------

extern "C" void kernel_launch(void* const* d_in, const int* in_sizes, int n_in,
                              void* d_out, int out_size, void* d_ws, size_t ws_size,
                              hipStream_t stream) {
    const float* x    = (const float*)d_in[0];
    const int*   ei   = (const int*)d_in[1];
    const int*   batch= (const int*)d_in[2];
    const float* W1   = (const float*)d_in[3];
    const float* b1   = (const float*)d_in[4];
    const float* W2   = (const float*)d_in[5];
    const float* b2   = (const float*)d_in[6];
    const float* W3   = (const float*)d_in[7];
    const float* b3   = (const float*)d_in[8];
    const float* linW = (const float*)d_in[9];
    const float* linb = (const float*)d_in[10];
    float* out = (float*)d_out;

    const int N = in_sizes[0] / FEAT;
    const int E = in_sizes[1] / 2;
    const int* row = ei;
    const int* col = ei + E;

    char* p = (char*)d_ws;
    auto alloc = [&](size_t bytes) { void* r = (void*)p; p += (bytes + 255) & ~(size_t)255; return r; };
    int*   hist    = (int*)  alloc((size_t)N * 4);
    int*   start   = (int*)  alloc((size_t)N * 4);
    int*   cur     = (int*)  alloc((size_t)N * 4);
    float* dinv    = (float*)alloc((size_t)N * 4);
    int*   csr_row = (int*)  alloc((size_t)E * 4);
    float* csr_w   = (float*)alloc((size_t)E * 4);
    int*   partial = (int*)  alloc(4096);
    float* tA      = (float*)alloc((size_t)N * FEAT * 4);
    float* tB      = (float*)alloc((size_t)N * FEAT * 4);
    float* pooled  = (float*)alloc((size_t)NGRAPH * FEAT * 4);
    float* cntf    = (float*)alloc((size_t)NGRAPH * 4);

    hipMemsetAsync(hist,   0, (size_t)N * 4, stream);
    hipMemsetAsync(pooled, 0, (size_t)NGRAPH * FEAT * 4, stream);
    hipMemsetAsync(cntf,   0, (size_t)NGRAPH * 4, stream);

    const int nscan = (N + 255) / 256;

    k_hist <<<(E + 255) / 256, 256, 0, stream>>>(col, hist, E);
    k_dinv <<<nscan, 256, 0, stream>>>(hist, dinv, N);
    k_scanA<<<nscan, 256, 0, stream>>>(hist, partial, N);
    k_scanB<<<1, 256, 0, stream>>>(partial, nscan);
    k_scanC<<<nscan, 256, 0, stream>>>(hist, partial, start, cur, N);
    k_fill <<<(E + 255) / 256, 256, 0, stream>>>(row, col, dinv, cur, csr_row, csr_w, E);

    const int gblk = (N + BM - 1) / BM;

    // layer 1: x -> tA -> tB
    k_gemm<<<gblk, 256, 0, stream>>>(x, W1, tA, N);
    k_agg <<<N, 128, 0, stream>>>(tA, csr_row, csr_w, start, cur, dinv, b1, tB, N, 1);
    // layer 2: tB -> tA -> tB
    k_gemm<<<gblk, 256, 0, stream>>>(tB, W2, tA, N);
    k_agg <<<N, 128, 0, stream>>>(tA, csr_row, csr_w, start, cur, dinv, b2, tB, N, 1);
    // layer 3: tB -> tA -> tB (no relu)
    k_gemm<<<gblk, 256, 0, stream>>>(tB, W3, tA, N);
    k_agg <<<N, 128, 0, stream>>>(tA, csr_row, csr_w, start, cur, dinv, b3, tB, N, 0);

    k_pool <<<(N * FEAT + 255) / 256, 256, 0, stream>>>(tB, batch, pooled, N);
    k_cnt  <<<nscan, 256, 0, stream>>>(batch, cntf, N);
    k_final<<<(NGRAPH * NCLS + 255) / 256, 256, 0, stream>>>(pooled, cntf, linW, linb, out);
}

// Round 5
// 477.298 us; speedup vs baseline: 1.2982x; 1.2982x over previous
//
#include <hip/hip_runtime.h>
#include <hip/hip_bf16.h>

#define FEAT 128
#define NGRAPH 512
#define NCLS 16

// ---------------- helpers ----------------

__device__ inline unsigned short f2bf(float f) {
    __hip_bfloat16 h = __float2bfloat16(f);          // round-to-nearest-even
    return *(unsigned short*)&h;
}
__device__ inline unsigned int pk2(float a, float b) {
    return (unsigned int)f2bf(a) | ((unsigned int)f2bf(b) << 16);
}
__device__ inline void unpk2(unsigned int u, float& lo, float& hi) {
    lo = __uint_as_float(u << 16);
    hi = __uint_as_float(u & 0xffff0000u);
}

// ---------------- CSR build ----------------

__global__ void k_hist(const int* __restrict__ col, int* __restrict__ hist, int E) {
    int i = blockIdx.x * blockDim.x + threadIdx.x;
    if (i < E) atomicAdd(&hist[col[i]], 1);
}

__global__ void k_dinv(const int* __restrict__ hist, float* __restrict__ dinv, int N) {
    int i = blockIdx.x * blockDim.x + threadIdx.x;
    if (i < N) dinv[i] = rsqrtf((float)(hist[i] + 1));   // +1 self loop, always > 0
}

__global__ void k_scanA(const int* __restrict__ hist, int* __restrict__ partial, int N) {
    __shared__ int s[256];
    int i = blockIdx.x * 256 + threadIdx.x;
    s[threadIdx.x] = (i < N) ? hist[i] : 0;
    __syncthreads();
    for (int off = 128; off > 0; off >>= 1) {
        if (threadIdx.x < off) s[threadIdx.x] += s[threadIdx.x + off];
        __syncthreads();
    }
    if (threadIdx.x == 0) partial[blockIdx.x] = s[0];
}

__global__ void k_scanB(int* __restrict__ partial, int nb) {
    __shared__ int s[256];
    int t = threadIdx.x;
    int orig = (t < nb) ? partial[t] : 0;
    s[t] = orig;
    __syncthreads();
    for (int off = 1; off < 256; off <<= 1) {
        int v = (t >= off) ? s[t - off] : 0;
        __syncthreads();
        s[t] += v;
        __syncthreads();
    }
    if (t < nb) partial[t] = s[t] - orig;   // exclusive
}

__global__ void k_scanC(const int* __restrict__ hist, const int* __restrict__ partial,
                        int* __restrict__ start, int* __restrict__ cur, int N) {
    __shared__ int s[256];
    int t = threadIdx.x;
    int i = blockIdx.x * 256 + t;
    int orig = (i < N) ? hist[i] : 0;
    s[t] = orig;
    __syncthreads();
    for (int off = 1; off < 256; off <<= 1) {
        int v = (t >= off) ? s[t - off] : 0;
        __syncthreads();
        s[t] += v;
        __syncthreads();
    }
    if (i < N) {
        int ex = s[t] - orig + partial[blockIdx.x];
        start[i] = ex;
        cur[i] = ex;
    }
}

__global__ void k_fill(const int* __restrict__ row, const int* __restrict__ col,
                       const float* __restrict__ dinv, int* __restrict__ cur,
                       int* __restrict__ csr_row, float* __restrict__ csr_w, int E) {
    int i = blockIdx.x * blockDim.x + threadIdx.x;
    if (i >= E) return;
    int r = row[i], c = col[i];
    int pos = atomicAdd(&cur[c], 1);
    csr_row[pos] = r;
    csr_w[pos] = dinv[r] * dinv[c];
}

// ---------------- dense transform: Cbf[M,128](bf16) = A[M,128] @ W[128,128] ----------------

#define BM 64
#define BK 32

__global__ __launch_bounds__(256) void k_gemm(const float* __restrict__ A,
                                              const float* __restrict__ W,
                                              unsigned int* __restrict__ Cbf, int M) {
    __shared__ float As[BM][BK + 1];
    __shared__ float Ws[BK][FEAT + 4];
    int tid = threadIdx.x;
    int m0 = blockIdx.x * BM;
    int ty = tid >> 4, tx = tid & 15;
    float acc[4][8] = {};

    for (int kt = 0; kt < FEAT; kt += BK) {
        for (int u = tid; u < BM * BK / 4; u += 256) {
            int ar = u >> 3, ac = (u & 7) * 4;
            int gr = m0 + ar;
            float4 v = make_float4(0.f, 0.f, 0.f, 0.f);
            if (gr < M) v = *(const float4*)&A[(size_t)gr * FEAT + kt + ac];
            As[ar][ac + 0] = v.x; As[ar][ac + 1] = v.y;
            As[ar][ac + 2] = v.z; As[ar][ac + 3] = v.w;
        }
        for (int u = tid; u < BK * FEAT / 4; u += 256) {
            int wr = u >> 5, wc = (u & 31) * 4;
            float4 v = *(const float4*)&W[(size_t)(kt + wr) * FEAT + wc];
            Ws[wr][wc + 0] = v.x; Ws[wr][wc + 1] = v.y;
            Ws[wr][wc + 2] = v.z; Ws[wr][wc + 3] = v.w;
        }
        __syncthreads();
        #pragma unroll
        for (int kk = 0; kk < BK; ++kk) {
            float a0 = As[ty * 4 + 0][kk];
            float a1 = As[ty * 4 + 1][kk];
            float a2 = As[ty * 4 + 2][kk];
            float a3 = As[ty * 4 + 3][kk];
            float b[8];
            *(float4*)&b[0] = *(float4*)&Ws[kk][tx * 8];
            *(float4*)&b[4] = *(float4*)&Ws[kk][tx * 8 + 4];
            #pragma unroll
            for (int j = 0; j < 8; ++j) {
                acc[0][j] = fmaf(a0, b[j], acc[0][j]);
                acc[1][j] = fmaf(a1, b[j], acc[1][j]);
                acc[2][j] = fmaf(a2, b[j], acc[2][j]);
                acc[3][j] = fmaf(a3, b[j], acc[3][j]);
            }
        }
        __syncthreads();
    }
    #pragma unroll
    for (int i = 0; i < 4; ++i) {
        int gr = m0 + ty * 4 + i;
        if (gr < M) {
            uint4 o;
            o.x = pk2(acc[i][0], acc[i][1]);
            o.y = pk2(acc[i][2], acc[i][3]);
            o.z = pk2(acc[i][4], acc[i][5]);
            o.w = pk2(acc[i][6], acc[i][7]);
            *(uint4*)&Cbf[(size_t)gr * (FEAT / 2) + tx * 4] = o;   // 8 bf16 = 16 B
        }
    }
}

// ---------------- aggregation (bf16 gather, fp32 accumulate) ----------------
// h[v,:] = sum_{e: col=v} tbf[row_e,:]*w_e + tbf[v,:]*dinv[v]^2 + b ; optional relu
// 32 lanes per node, 4 features per lane (uint2 = 4 bf16 = 8 B per edge per lane)

__global__ __launch_bounds__(256) void k_agg(const uint2* __restrict__ tbf,
                                             const int* __restrict__ csr_row,
                                             const float* __restrict__ csr_w,
                                             const int* __restrict__ start,
                                             const int* __restrict__ endp,
                                             const float* __restrict__ dinv,
                                             const float* __restrict__ bias,
                                             float* __restrict__ h, int N, int do_relu) {
    int t = threadIdx.x;
    int v = blockIdx.x * 8 + (t >> 5);
    if (v >= N) return;
    int lane = t & 31;

    float a0, a1, a2, a3;
    {   // self loop
        float dv = dinv[v];
        float ws = dv * dv;
        uint2 sv = tbf[(size_t)v * 32 + lane];
        float f0, f1, f2, f3;
        unpk2(sv.x, f0, f1); unpk2(sv.y, f2, f3);
        a0 = f0 * ws; a1 = f1 * ws; a2 = f2 * ws; a3 = f3 * ws;
    }

    int s = start[v], e = endp[v];
    int p = s;
    for (; p + 4 <= e; p += 4) {
        int r0 = csr_row[p], r1 = csr_row[p + 1], r2 = csr_row[p + 2], r3 = csr_row[p + 3];
        float w0 = csr_w[p], w1 = csr_w[p + 1], w2 = csr_w[p + 2], w3 = csr_w[p + 3];
        uint2 g0 = tbf[(size_t)r0 * 32 + lane];
        uint2 g1 = tbf[(size_t)r1 * 32 + lane];
        uint2 g2 = tbf[(size_t)r2 * 32 + lane];
        uint2 g3 = tbf[(size_t)r3 * 32 + lane];
        float f0, f1, f2, f3;
        unpk2(g0.x, f0, f1); unpk2(g0.y, f2, f3);
        a0 = fmaf(f0, w0, a0); a1 = fmaf(f1, w0, a1); a2 = fmaf(f2, w0, a2); a3 = fmaf(f3, w0, a3);
        unpk2(g1.x, f0, f1); unpk2(g1.y, f2, f3);
        a0 = fmaf(f0, w1, a0); a1 = fmaf(f1, w1, a1); a2 = fmaf(f2, w1, a2); a3 = fmaf(f3, w1, a3);
        unpk2(g2.x, f0, f1); unpk2(g2.y, f2, f3);
        a0 = fmaf(f0, w2, a0); a1 = fmaf(f1, w2, a1); a2 = fmaf(f2, w2, a2); a3 = fmaf(f3, w2, a3);
        unpk2(g3.x, f0, f1); unpk2(g3.y, f2, f3);
        a0 = fmaf(f0, w3, a0); a1 = fmaf(f1, w3, a1); a2 = fmaf(f2, w3, a2); a3 = fmaf(f3, w3, a3);
    }
    for (; p < e; ++p) {
        int r = csr_row[p];
        float w = csr_w[p];
        uint2 g = tbf[(size_t)r * 32 + lane];
        float f0, f1, f2, f3;
        unpk2(g.x, f0, f1); unpk2(g.y, f2, f3);
        a0 = fmaf(f0, w, a0); a1 = fmaf(f1, w, a1); a2 = fmaf(f2, w, a2); a3 = fmaf(f3, w, a3);
    }

    float4 b4 = *(const float4*)&bias[lane * 4];
    a0 += b4.x; a1 += b4.y; a2 += b4.z; a3 += b4.w;
    if (do_relu) {
        a0 = fmaxf(a0, 0.f); a1 = fmaxf(a1, 0.f);
        a2 = fmaxf(a2, 0.f); a3 = fmaxf(a3, 0.f);
    }
    *(float4*)&h[(size_t)v * FEAT + lane * 4] = make_float4(a0, a1, a2, a3);
}

// ---------------- pooling (batch is sorted) + classifier ----------------

__global__ void k_gcnt(const int* __restrict__ batch, int* __restrict__ gcnt, int N) {
    int v = blockIdx.x * blockDim.x + threadIdx.x;
    if (v < N) atomicAdd(&gcnt[batch[v]], 1);
}

__global__ void k_goff(const int* __restrict__ gcnt, int* __restrict__ goff,
                       float* __restrict__ cntf) {
    __shared__ int s[NGRAPH];
    int t = threadIdx.x;
    int v = gcnt[t];
    s[t] = v;
    __syncthreads();
    for (int off = 1; off < NGRAPH; off <<= 1) {
        int u = (t >= off) ? s[t - off] : 0;
        __syncthreads();
        s[t] += u;
        __syncthreads();
    }
    goff[t] = s[t] - v;   // exclusive
    cntf[t] = (float)v;
}

__global__ __launch_bounds__(128) void k_pool(const float* __restrict__ h,
                                              const int* __restrict__ goff,
                                              const int* __restrict__ gcnt,
                                              float* __restrict__ pooled) {
    int g = blockIdx.x, t = threadIdx.x;
    int s = goff[g], n = gcnt[g];
    float acc = 0.f;
    for (int i = 0; i < n; ++i) acc += h[(size_t)(s + i) * FEAT + t];
    pooled[g * FEAT + t] = acc / fmaxf((float)n, 1.f);
}

__global__ void k_final(const float* __restrict__ pooled,
                        const float* __restrict__ linW, const float* __restrict__ linb,
                        float* __restrict__ out) {
    int idx = blockIdx.x * blockDim.x + threadIdx.x;
    if (idx >= NGRAPH * NCLS) return;
    int g = idx >> 4, c = idx & 15;
    float acc = 0.f;
    #pragma unroll 8
    for (int jj = 0; jj < FEAT; ++jj)
        acc = fmaf(pooled[g * FEAT + jj], linW[jj * NCLS + c], acc);
    out[idx] = acc + linb[c];
}

// ---------------- launch ----------------

extern "C" void kernel_launch(void* const* d_in, const int* in_sizes, int n_in,
                              void* d_out, int out_size, void* d_ws, size_t ws_size,
                              hipStream_t stream) {
    const float* x    = (const float*)d_in[0];
    const int*   ei   = (const int*)d_in[1];
    const int*   batch= (const int*)d_in[2];
    const float* W1   = (const float*)d_in[3];
    const float* b1   = (const float*)d_in[4];
    const float* W2   = (const float*)d_in[5];
    const float* b2   = (const float*)d_in[6];
    const float* W3   = (const float*)d_in[7];
    const float* b3   = (const float*)d_in[8];
    const float* linW = (const float*)d_in[9];
    const float* linb = (const float*)d_in[10];
    float* out = (float*)d_out;

    const int N = in_sizes[0] / FEAT;
    const int E = in_sizes[1] / 2;
    const int* row = ei;
    const int* col = ei + E;

    char* p = (char*)d_ws;
    auto alloc = [&](size_t bytes) { void* r = (void*)p; p += (bytes + 255) & ~(size_t)255; return r; };
    int*   hist    = (int*)  alloc((size_t)N * 4);
    int*   start   = (int*)  alloc((size_t)N * 4);
    int*   cur     = (int*)  alloc((size_t)N * 4);
    float* dinv    = (float*)alloc((size_t)N * 4);
    int*   csr_row = (int*)  alloc((size_t)E * 4);
    float* csr_w   = (float*)alloc((size_t)E * 4);
    int*   partial = (int*)  alloc(4096);
    unsigned int* tbf = (unsigned int*)alloc((size_t)N * FEAT * 2);   // bf16 [N,128]
    float* h       = (float*)alloc((size_t)N * FEAT * 4);
    float* pooled  = (float*)alloc((size_t)NGRAPH * FEAT * 4);
    float* cntf    = (float*)alloc((size_t)NGRAPH * 4);
    int*   gcnt    = (int*)  alloc((size_t)NGRAPH * 4);
    int*   goff    = (int*)  alloc((size_t)NGRAPH * 4);

    hipMemsetAsync(hist, 0, (size_t)N * 4, stream);
    hipMemsetAsync(gcnt, 0, (size_t)NGRAPH * 4, stream);

    const int nscan = (N + 255) / 256;

    k_hist <<<(E + 255) / 256, 256, 0, stream>>>(col, hist, E);
    k_dinv <<<nscan, 256, 0, stream>>>(hist, dinv, N);
    k_scanA<<<nscan, 256, 0, stream>>>(hist, partial, N);
    k_scanB<<<1, 256, 0, stream>>>(partial, nscan);
    k_scanC<<<nscan, 256, 0, stream>>>(hist, partial, start, cur, N);
    k_fill <<<(E + 255) / 256, 256, 0, stream>>>(row, col, dinv, cur, csr_row, csr_w, E);
    k_gcnt <<<nscan, 256, 0, stream>>>(batch, gcnt, N);
    k_goff <<<1, NGRAPH, 0, stream>>>(gcnt, goff, cntf);

    const int gblk = (N + BM - 1) / BM;
    const int ablk = (N + 7) / 8;

    k_gemm<<<gblk, 256, 0, stream>>>(x, W1, tbf, N);
    k_agg <<<ablk, 256, 0, stream>>>((const uint2*)tbf, csr_row, csr_w, start, cur, dinv, b1, h, N, 1);
    k_gemm<<<gblk, 256, 0, stream>>>(h, W2, tbf, N);
    k_agg <<<ablk, 256, 0, stream>>>((const uint2*)tbf, csr_row, csr_w, start, cur, dinv, b2, h, N, 1);
    k_gemm<<<gblk, 256, 0, stream>>>(h, W3, tbf, N);
    k_agg <<<ablk, 256, 0, stream>>>((const uint2*)tbf, csr_row, csr_w, start, cur, dinv, b3, h, N, 0);

    k_pool <<<NGRAPH, 128, 0, stream>>>(h, goff, gcnt, pooled);
    k_final<<<(NGRAPH * NCLS + 255) / 256, 256, 0, stream>>>(pooled, linW, linb, out);
}

// Round 14
// 426.049 us; speedup vs baseline: 1.4543x; 1.1203x over previous
//
#include <hip/hip_runtime.h>
#include <hip/hip_bf16.h>

#define FEAT 128
#define NGRAPH 512
#define NCLS 16

typedef __attribute__((ext_vector_type(8))) short bf16x8;
typedef __attribute__((ext_vector_type(4))) float f32x4;

// ---------------- helpers ----------------

__device__ inline unsigned short f2bf(float f) {
    __hip_bfloat16 h = __float2bfloat16(f);          // round-to-nearest-even
    return *(unsigned short*)&h;
}
__device__ inline float bf2f(unsigned short u) {
    return __uint_as_float((unsigned int)u << 16);
}
__device__ inline void unpk2(unsigned int u, float& lo, float& hi) {
    lo = __uint_as_float(u << 16);
    hi = __uint_as_float(u & 0xffff0000u);
}

// ---------------- CSR build ----------------

__global__ void k_hist(const int* __restrict__ col, int* __restrict__ hist, int E) {
    int i = blockIdx.x * blockDim.x + threadIdx.x;
    if (i < E) atomicAdd(&hist[col[i]], 1);
}

__global__ void k_dinv(const int* __restrict__ hist, float* __restrict__ dinv, int N) {
    int i = blockIdx.x * blockDim.x + threadIdx.x;
    if (i < N) dinv[i] = rsqrtf((float)(hist[i] + 1));   // +1 self loop, always > 0
}

__global__ void k_scanA(const int* __restrict__ hist, int* __restrict__ partial, int N) {
    __shared__ int s[256];
    int i = blockIdx.x * 256 + threadIdx.x;
    s[threadIdx.x] = (i < N) ? hist[i] : 0;
    __syncthreads();
    for (int off = 128; off > 0; off >>= 1) {
        if (threadIdx.x < off) s[threadIdx.x] += s[threadIdx.x + off];
        __syncthreads();
    }
    if (threadIdx.x == 0) partial[blockIdx.x] = s[0];
}

__global__ void k_scanB(int* __restrict__ partial, int nb) {
    __shared__ int s[256];
    int t = threadIdx.x;
    int orig = (t < nb) ? partial[t] : 0;
    s[t] = orig;
    __syncthreads();
    for (int off = 1; off < 256; off <<= 1) {
        int v = (t >= off) ? s[t - off] : 0;
        __syncthreads();
        s[t] += v;
        __syncthreads();
    }
    if (t < nb) partial[t] = s[t] - orig;   // exclusive
}

__global__ void k_scanC(const int* __restrict__ hist, const int* __restrict__ partial,
                        int* __restrict__ start, int* __restrict__ cur, int N) {
    __shared__ int s[256];
    int t = threadIdx.x;
    int i = blockIdx.x * 256 + t;
    int orig = (i < N) ? hist[i] : 0;
    s[t] = orig;
    __syncthreads();
    for (int off = 1; off < 256; off <<= 1) {
        int v = (t >= off) ? s[t - off] : 0;
        __syncthreads();
        s[t] += v;
        __syncthreads();
    }
    if (i < N) {
        int ex = s[t] - orig + partial[blockIdx.x];
        start[i] = ex;
        cur[i] = ex;
    }
}

// csr_w eliminated: weights are folded into the bf16 table (pre-scaled by dinv[row])
__global__ void k_fill(const int* __restrict__ row, const int* __restrict__ col,
                       int* __restrict__ cur, int* __restrict__ csr_row, int E) {
    int i = blockIdx.x * blockDim.x + threadIdx.x;
    if (i >= E) return;
    int r = row[i], c = col[i];
    int pos = atomicAdd(&cur[c], 1);
    csr_row[pos] = r;
}

// ---------------- W split into fragment-ordered bf16 hi/lo ----------------
// Wsplit[kt][cb][lane][j] = W[kt*32 + (lane>>4)*8 + j][cb*16 + (lane&15)]
// (B-operand layout of mfma_f32_16x16x32_bf16); 3 layers in one launch.

__global__ void k_wsplit(const float* __restrict__ W1, const float* __restrict__ W2,
                         const float* __restrict__ W3,
                         bf16x8* __restrict__ whi, bf16x8* __restrict__ wlo) {
    int tid = blockIdx.x * 256 + threadIdx.x;      // 3 * 2048
    int layer = tid >> 11;
    int r = tid & 2047;
    int kt = r >> 9, cb = (r >> 6) & 7, lane = r & 63;
    const float* W = (layer == 0) ? W1 : (layer == 1) ? W2 : W3;
    bf16x8 hi, lo;
    #pragma unroll
    for (int j = 0; j < 8; ++j) {
        float w = W[(size_t)(kt * 32 + (lane >> 4) * 8 + j) * FEAT + cb * 16 + (lane & 15)];
        unsigned short hb = f2bf(w);
        hi[j] = (short)hb;
        lo[j] = (short)f2bf(w - bf2f(hb));
    }
    size_t idx = (size_t)layer * 2048 + (kt * 8 + cb) * 64 + lane;
    whi[idx] = hi;
    wlo[idx] = lo;
}

// ---------------- dense transform (MFMA, split-bf16 for fp32 accuracy) ----------------
// tbf[r,:] = bf16( (A[r,:] @ W) * dinv[r] )   — table is pre-scaled by dinv[row]

__global__ __launch_bounds__(256) void k_gemm(const float* __restrict__ A,
                                              const bf16x8* __restrict__ Whi,
                                              const bf16x8* __restrict__ Wlo,
                                              const float* __restrict__ dinv,
                                              unsigned short* __restrict__ tbf, int M) {
    int tid = threadIdx.x;
    int wave = tid >> 6, lane = tid & 63;
    int m0 = blockIdx.x * 64 + wave * 16;
    int aclamp = min(m0 + (lane & 15), M - 1);
    int kgrp = lane >> 4;                           // 0..3

    f32x4 acc[8];
    #pragma unroll
    for (int c = 0; c < 8; ++c) acc[c] = (f32x4){0.f, 0.f, 0.f, 0.f};

    #pragma unroll
    for (int kt = 0; kt < 4; ++kt) {
        const float* ap = A + (size_t)aclamp * FEAT + kt * 32 + kgrp * 8;
        float av[8];
        *(float4*)&av[0] = *(const float4*)ap;
        *(float4*)&av[4] = *(const float4*)(ap + 4);
        bf16x8 ahi, alo;
        #pragma unroll
        for (int j = 0; j < 8; ++j) {
            unsigned short hb = f2bf(av[j]);
            ahi[j] = (short)hb;
            alo[j] = (short)f2bf(av[j] - bf2f(hb));
        }
        #pragma unroll
        for (int cb = 0; cb < 8; ++cb) {
            bf16x8 bh = Whi[(kt * 8 + cb) * 64 + lane];
            bf16x8 bl = Wlo[(kt * 8 + cb) * 64 + lane];
            acc[cb] = __builtin_amdgcn_mfma_f32_16x16x32_bf16(ahi, bh, acc[cb], 0, 0, 0);
            acc[cb] = __builtin_amdgcn_mfma_f32_16x16x32_bf16(alo, bh, acc[cb], 0, 0, 0);
            acc[cb] = __builtin_amdgcn_mfma_f32_16x16x32_bf16(ahi, bl, acc[cb], 0, 0, 0);
        }
    }

    // D layout: row = (lane>>4)*4 + reg, col = lane&15  [measured: learn_hip m89]
    int rbase = m0 + (lane >> 4) * 4;
    int colb = lane & 15;
    #pragma unroll
    for (int r = 0; r < 4; ++r) {
        int gr = rbase + r;
        if (gr < M) {
            float dv = dinv[gr];
            #pragma unroll
            for (int cb = 0; cb < 8; ++cb)
                tbf[(size_t)gr * FEAT + cb * 16 + colb] = f2bf(acc[cb][r] * dv);
        }
    }
}

// ---------------- aggregation (bf16 gather of pre-scaled table) ----------------
// h[v,:] = dinv[v] * ( tbf[v,:] + sum_{e: col=v} tbf[row_e,:] ) + b ; optional relu

__global__ __launch_bounds__(256) void k_agg(const uint2* __restrict__ tbf,
                                             const int* __restrict__ csr_row,
                                             const int* __restrict__ start,
                                             const int* __restrict__ endp,
                                             const float* __restrict__ dinv,
                                             const float* __restrict__ bias,
                                             float* __restrict__ h, int N, int do_relu) {
    int t = threadIdx.x;
    int v = blockIdx.x * 8 + (t >> 5);
    if (v >= N) return;
    int lane = t & 31;

    float a0, a1, a2, a3;
    {   // self loop term (table already scaled by dinv[v])
        uint2 sv = tbf[(size_t)v * 32 + lane];
        unpk2(sv.x, a0, a1); unpk2(sv.y, a2, a3);
    }

    int s = start[v], e = endp[v];
    int p = s;
    for (; p + 4 <= e; p += 4) {
        int r0 = csr_row[p], r1 = csr_row[p + 1], r2 = csr_row[p + 2], r3 = csr_row[p + 3];
        uint2 g0 = tbf[(size_t)r0 * 32 + lane];
        uint2 g1 = tbf[(size_t)r1 * 32 + lane];
        uint2 g2 = tbf[(size_t)r2 * 32 + lane];
        uint2 g3 = tbf[(size_t)r3 * 32 + lane];
        float f0, f1, f2, f3;
        unpk2(g0.x, f0, f1); unpk2(g0.y, f2, f3);
        a0 += f0; a1 += f1; a2 += f2; a3 += f3;
        unpk2(g1.x, f0, f1); unpk2(g1.y, f2, f3);
        a0 += f0; a1 += f1; a2 += f2; a3 += f3;
        unpk2(g2.x, f0, f1); unpk2(g2.y, f2, f3);
        a0 += f0; a1 += f1; a2 += f2; a3 += f3;
        unpk2(g3.x, f0, f1); unpk2(g3.y, f2, f3);
        a0 += f0; a1 += f1; a2 += f2; a3 += f3;
    }
    for (; p < e; ++p) {
        int r = csr_row[p];
        uint2 g = tbf[(size_t)r * 32 + lane];
        float f0, f1, f2, f3;
        unpk2(g.x, f0, f1); unpk2(g.y, f2, f3);
        a0 += f0; a1 += f1; a2 += f2; a3 += f3;
    }

    float dv = dinv[v];
    float4 b4 = *(const float4*)&bias[lane * 4];
    a0 = fmaf(a0, dv, b4.x); a1 = fmaf(a1, dv, b4.y);
    a2 = fmaf(a2, dv, b4.z); a3 = fmaf(a3, dv, b4.w);
    if (do_relu) {
        a0 = fmaxf(a0, 0.f); a1 = fmaxf(a1, 0.f);
        a2 = fmaxf(a2, 0.f); a3 = fmaxf(a3, 0.f);
    }
    *(float4*)&h[(size_t)v * FEAT + lane * 4] = make_float4(a0, a1, a2, a3);
}

// ---------------- pooling (batch is sorted) + classifier ----------------

__global__ void k_gcnt(const int* __restrict__ batch, int* __restrict__ gcnt, int N) {
    int v = blockIdx.x * blockDim.x + threadIdx.x;
    if (v < N) atomicAdd(&gcnt[batch[v]], 1);
}

__global__ void k_goff(const int* __restrict__ gcnt, int* __restrict__ goff,
                       float* __restrict__ cntf) {
    __shared__ int s[NGRAPH];
    int t = threadIdx.x;
    int v = gcnt[t];
    s[t] = v;
    __syncthreads();
    for (int off = 1; off < NGRAPH; off <<= 1) {
        int u = (t >= off) ? s[t - off] : 0;
        __syncthreads();
        s[t] += u;
        __syncthreads();
    }
    goff[t] = s[t] - v;   // exclusive
    cntf[t] = (float)v;
}

__global__ __launch_bounds__(128) void k_pool(const float* __restrict__ h,
                                              const int* __restrict__ goff,
                                              const int* __restrict__ gcnt,
                                              float* __restrict__ pooled) {
    int g = blockIdx.x, t = threadIdx.x;
    int s = goff[g], n = gcnt[g];
    float acc = 0.f;
    for (int i = 0; i < n; ++i) acc += h[(size_t)(s + i) * FEAT + t];
    pooled[g * FEAT + t] = acc / fmaxf((float)n, 1.f);
}

__global__ void k_final(const float* __restrict__ pooled,
                        const float* __restrict__ linW, const float* __restrict__ linb,
                        float* __restrict__ out) {
    int idx = blockIdx.x * blockDim.x + threadIdx.x;
    if (idx >= NGRAPH * NCLS) return;
    int g = idx >> 4, c = idx & 15;
    float acc = 0.f;
    #pragma unroll 8
    for (int jj = 0; jj < FEAT; ++jj)
        acc = fmaf(pooled[g * FEAT + jj], linW[jj * NCLS + c], acc);
    out[idx] = acc + linb[c];
}

// ---------------- launch ----------------

extern "C" void kernel_launch(void* const* d_in, const int* in_sizes, int n_in,
                              void* d_out, int out_size, void* d_ws, size_t ws_size,
                              hipStream_t stream) {
    const float* x    = (const float*)d_in[0];
    const int*   ei   = (const int*)d_in[1];
    const int*   batch= (const int*)d_in[2];
    const float* W1   = (const float*)d_in[3];
    const float* b1   = (const float*)d_in[4];
    const float* W2   = (const float*)d_in[5];
    const float* b2   = (const float*)d_in[6];
    const float* W3   = (const float*)d_in[7];
    const float* b3   = (const float*)d_in[8];
    const float* linW = (const float*)d_in[9];
    const float* linb = (const float*)d_in[10];
    float* out = (float*)d_out;

    const int N = in_sizes[0] / FEAT;
    const int E = in_sizes[1] / 2;
    const int* row = ei;
    const int* col = ei + E;

    char* p = (char*)d_ws;
    auto alloc = [&](size_t bytes) { void* r = (void*)p; p += (bytes + 255) & ~(size_t)255; return r; };
    int*   hist    = (int*)  alloc((size_t)N * 4);
    int*   start   = (int*)  alloc((size_t)N * 4);
    int*   cur     = (int*)  alloc((size_t)N * 4);
    float* dinv    = (float*)alloc((size_t)N * 4);
    int*   csr_row = (int*)  alloc((size_t)E * 4);
    int*   partial = (int*)  alloc(4096);
    unsigned short* tbf = (unsigned short*)alloc((size_t)N * FEAT * 2); // bf16 [N,128], pre-scaled
    float* h       = (float*)alloc((size_t)N * FEAT * 4);
    bf16x8* whi    = (bf16x8*)alloc(3 * 2048 * sizeof(bf16x8));
    bf16x8* wlo    = (bf16x8*)alloc(3 * 2048 * sizeof(bf16x8));
    float* pooled  = (float*)alloc((size_t)NGRAPH * FEAT * 4);
    float* cntf    = (float*)alloc((size_t)NGRAPH * 4);
    int*   gcnt    = (int*)  alloc((size_t)NGRAPH * 4);
    int*   goff    = (int*)  alloc((size_t)NGRAPH * 4);

    hipMemsetAsync(hist, 0, (size_t)N * 4, stream);
    hipMemsetAsync(gcnt, 0, (size_t)NGRAPH * 4, stream);

    const int nscan = (N + 255) / 256;

    k_hist  <<<(E + 255) / 256, 256, 0, stream>>>(col, hist, E);
    k_dinv  <<<nscan, 256, 0, stream>>>(hist, dinv, N);
    k_scanA <<<nscan, 256, 0, stream>>>(hist, partial, N);
    k_scanB <<<1, 256, 0, stream>>>(partial, nscan);
    k_scanC <<<nscan, 256, 0, stream>>>(hist, partial, start, cur, N);
    k_fill  <<<(E + 255) / 256, 256, 0, stream>>>(row, col, cur, csr_row, E);
    k_wsplit<<<24, 256, 0, stream>>>(W1, W2, W3, whi, wlo);
    k_gcnt  <<<nscan, 256, 0, stream>>>(batch, gcnt, N);
    k_goff  <<<1, NGRAPH, 0, stream>>>(gcnt, goff, cntf);

    const int gblk = (N + 63) / 64;
    const int ablk = (N + 7) / 8;

    k_gemm<<<gblk, 256, 0, stream>>>(x, whi,        wlo,        dinv, tbf, N);
    k_agg <<<ablk, 256, 0, stream>>>((const uint2*)tbf, csr_row, start, cur, dinv, b1, h, N, 1);
    k_gemm<<<gblk, 256, 0, stream>>>(h, whi + 2048, wlo + 2048, dinv, tbf, N);
    k_agg <<<ablk, 256, 0, stream>>>((const uint2*)tbf, csr_row, start, cur, dinv, b2, h, N, 1);
    k_gemm<<<gblk, 256, 0, stream>>>(h, whi + 4096, wlo + 4096, dinv, tbf, N);
    k_agg <<<ablk, 256, 0, stream>>>((const uint2*)tbf, csr_row, start, cur, dinv, b3, h, N, 0);

    k_pool <<<NGRAPH, 128, 0, stream>>>(h, goff, gcnt, pooled);
    k_final<<<(NGRAPH * NCLS + 255) / 256, 256, 0, stream>>>(pooled, linW, linb, out);
}

// Round 18
// 423.165 us; speedup vs baseline: 1.4642x; 1.0068x over previous
//
#include <hip/hip_runtime.h>
#include <hip/hip_bf16.h>

#define FEAT 128
#define NGRAPH 512
#define NCLS 16

typedef __attribute__((ext_vector_type(8))) short bf16x8;
typedef __attribute__((ext_vector_type(4))) float f32x4;

// ---------------- helpers ----------------

__device__ inline unsigned short f2bf(float f) {
    __hip_bfloat16 h = __float2bfloat16(f);          // round-to-nearest-even
    return *(unsigned short*)&h;
}
__device__ inline float bf2f(unsigned short u) {
    return __uint_as_float((unsigned int)u << 16);
}
__device__ inline unsigned int pk2(float a, float b) {
    return (unsigned int)f2bf(a) | ((unsigned int)f2bf(b) << 16);
}
__device__ inline void unpk2(unsigned int u, float& lo, float& hi) {
    lo = __uint_as_float(u << 16);
    hi = __uint_as_float(u & 0xffff0000u);
}

// ---------------- CSR build ----------------

__global__ void k_hist(const int* __restrict__ col, int* __restrict__ hist, int E) {
    int i = blockIdx.x * blockDim.x + threadIdx.x;
    if (i < E) atomicAdd(&hist[col[i]], 1);
}

__global__ void k_dinv(const int* __restrict__ hist, float* __restrict__ dinv, int N) {
    int i = blockIdx.x * blockDim.x + threadIdx.x;
    if (i < N) dinv[i] = rsqrtf((float)(hist[i] + 1));   // +1 self loop, always > 0
}

__global__ void k_scanA(const int* __restrict__ hist, int* __restrict__ partial, int N) {
    __shared__ int s[256];
    int i = blockIdx.x * 256 + threadIdx.x;
    s[threadIdx.x] = (i < N) ? hist[i] : 0;
    __syncthreads();
    for (int off = 128; off > 0; off >>= 1) {
        if (threadIdx.x < off) s[threadIdx.x] += s[threadIdx.x + off];
        __syncthreads();
    }
    if (threadIdx.x == 0) partial[blockIdx.x] = s[0];
}

__global__ void k_scanB(int* __restrict__ partial, int nb) {
    __shared__ int s[256];
    int t = threadIdx.x;
    int orig = (t < nb) ? partial[t] : 0;
    s[t] = orig;
    __syncthreads();
    for (int off = 1; off < 256; off <<= 1) {
        int v = (t >= off) ? s[t - off] : 0;
        __syncthreads();
        s[t] += v;
        __syncthreads();
    }
    if (t < nb) partial[t] = s[t] - orig;   // exclusive
}

__global__ void k_scanC(const int* __restrict__ hist, const int* __restrict__ partial,
                        int* __restrict__ start, int* __restrict__ cur, int N) {
    __shared__ int s[256];
    int t = threadIdx.x;
    int i = blockIdx.x * 256 + t;
    int orig = (i < N) ? hist[i] : 0;
    s[t] = orig;
    __syncthreads();
    for (int off = 1; off < 256; off <<= 1) {
        int v = (t >= off) ? s[t - off] : 0;
        __syncthreads();
        s[t] += v;
        __syncthreads();
    }
    if (i < N) {
        int ex = s[t] - orig + partial[blockIdx.x];
        start[i] = ex;
        cur[i] = ex;
    }
}

// ushort indices (N < 65536) + non-temporal store: partial-line scatters merge in the
// memory-side cache instead of 8 private XCD L2s each writing back 64B dirty lines.
__global__ void k_fill(const int* __restrict__ row, const int* __restrict__ col,
                       int* __restrict__ cur, unsigned short* __restrict__ csr_row, int E) {
    int i = blockIdx.x * blockDim.x + threadIdx.x;
    if (i >= E) return;
    int r = row[i], c = col[i];
    int pos = atomicAdd(&cur[c], 1);
    __builtin_nontemporal_store((unsigned short)r, &csr_row[pos]);
}

// ---------------- W split into fragment-ordered bf16 hi/lo ----------------
// Wsplit[kt][cb][lane][j] = W[kt*32 + (lane>>4)*8 + j][cb*16 + (lane&15)]

__global__ void k_wsplit(const float* __restrict__ W1, const float* __restrict__ W2,
                         const float* __restrict__ W3,
                         bf16x8* __restrict__ whi, bf16x8* __restrict__ wlo) {
    int tid = blockIdx.x * 256 + threadIdx.x;      // 3 * 2048
    int layer = tid >> 11;
    int r = tid & 2047;
    int kt = r >> 9, cb = (r >> 6) & 7, lane = r & 63;
    const float* W = (layer == 0) ? W1 : (layer == 1) ? W2 : W3;
    bf16x8 hi, lo;
    #pragma unroll
    for (int j = 0; j < 8; ++j) {
        float w = W[(size_t)(kt * 32 + (lane >> 4) * 8 + j) * FEAT + cb * 16 + (lane & 15)];
        unsigned short hb = f2bf(w);
        hi[j] = (short)hb;
        lo[j] = (short)f2bf(w - bf2f(hb));
    }
    size_t idx = (size_t)layer * 2048 + (kt * 8 + cb) * 64 + lane;
    whi[idx] = hi;
    wlo[idx] = lo;
}

// ---------------- dense transform, fp32 A (layer 1): split-bf16, 3 MFMA ----------------
// tbf[r,:] = bf16( (A[r,:] @ W) * dinv[r] )

__global__ __launch_bounds__(256) void k_gemm_f32(const float* __restrict__ A,
                                                  const bf16x8* __restrict__ Whi,
                                                  const bf16x8* __restrict__ Wlo,
                                                  const float* __restrict__ dinv,
                                                  unsigned short* __restrict__ tbf, int M) {
    int tid = threadIdx.x;
    int wave = tid >> 6, lane = tid & 63;
    int m0 = blockIdx.x * 64 + wave * 16;
    int aclamp = min(m0 + (lane & 15), M - 1);
    int kgrp = lane >> 4;                           // 0..3

    f32x4 acc[8];
    #pragma unroll
    for (int c = 0; c < 8; ++c) acc[c] = (f32x4){0.f, 0.f, 0.f, 0.f};

    #pragma unroll
    for (int kt = 0; kt < 4; ++kt) {
        const float* ap = A + (size_t)aclamp * FEAT + kt * 32 + kgrp * 8;
        float av[8];
        *(float4*)&av[0] = *(const float4*)ap;
        *(float4*)&av[4] = *(const float4*)(ap + 4);
        bf16x8 ahi, alo;
        #pragma unroll
        for (int j = 0; j < 8; ++j) {
            unsigned short hb = f2bf(av[j]);
            ahi[j] = (short)hb;
            alo[j] = (short)f2bf(av[j] - bf2f(hb));
        }
        #pragma unroll
        for (int cb = 0; cb < 8; ++cb) {
            bf16x8 bh = Whi[(kt * 8 + cb) * 64 + lane];
            bf16x8 bl = Wlo[(kt * 8 + cb) * 64 + lane];
            acc[cb] = __builtin_amdgcn_mfma_f32_16x16x32_bf16(ahi, bh, acc[cb], 0, 0, 0);
            acc[cb] = __builtin_amdgcn_mfma_f32_16x16x32_bf16(alo, bh, acc[cb], 0, 0, 0);
            acc[cb] = __builtin_amdgcn_mfma_f32_16x16x32_bf16(ahi, bl, acc[cb], 0, 0, 0);
        }
    }

    // D layout: row = (lane>>4)*4 + reg, col = lane&15  [measured: learn_hip m89]
    int rbase = m0 + (lane >> 4) * 4;
    int colb = lane & 15;
    #pragma unroll
    for (int r = 0; r < 4; ++r) {
        int gr = rbase + r;
        if (gr < M) {
            float dv = dinv[gr];
            #pragma unroll
            for (int cb = 0; cb < 8; ++cb)
                tbf[(size_t)gr * FEAT + cb * 16 + colb] = f2bf(acc[cb][r] * dv);
        }
    }
}

// ---------------- dense transform, bf16 A (layers 2,3): 2 MFMA ----------------

__global__ __launch_bounds__(256) void k_gemm_bf16(const unsigned short* __restrict__ Abf,
                                                   const bf16x8* __restrict__ Whi,
                                                   const bf16x8* __restrict__ Wlo,
                                                   const float* __restrict__ dinv,
                                                   unsigned short* __restrict__ tbf, int M) {
    int tid = threadIdx.x;
    int wave = tid >> 6, lane = tid & 63;
    int m0 = blockIdx.x * 64 + wave * 16;
    int aclamp = min(m0 + (lane & 15), M - 1);
    int kgrp = lane >> 4;

    f32x4 acc[8];
    #pragma unroll
    for (int c = 0; c < 8; ++c) acc[c] = (f32x4){0.f, 0.f, 0.f, 0.f};

    #pragma unroll
    for (int kt = 0; kt < 4; ++kt) {
        bf16x8 ahi = *(const bf16x8*)(Abf + (size_t)aclamp * FEAT + kt * 32 + kgrp * 8);
        #pragma unroll
        for (int cb = 0; cb < 8; ++cb) {
            bf16x8 bh = Whi[(kt * 8 + cb) * 64 + lane];
            bf16x8 bl = Wlo[(kt * 8 + cb) * 64 + lane];
            acc[cb] = __builtin_amdgcn_mfma_f32_16x16x32_bf16(ahi, bh, acc[cb], 0, 0, 0);
            acc[cb] = __builtin_amdgcn_mfma_f32_16x16x32_bf16(ahi, bl, acc[cb], 0, 0, 0);
        }
    }

    int rbase = m0 + (lane >> 4) * 4;
    int colb = lane & 15;
    #pragma unroll
    for (int r = 0; r < 4; ++r) {
        int gr = rbase + r;
        if (gr < M) {
            float dv = dinv[gr];
            #pragma unroll
            for (int cb = 0; cb < 8; ++cb)
                tbf[(size_t)gr * FEAT + cb * 16 + colb] = f2bf(acc[cb][r] * dv);
        }
    }
}

// ---------------- aggregation (bf16 gather of pre-scaled table) ----------------
// h[v,:] = dinv[v] * ( tbf[v,:] + sum_{e: col=v} tbf[row_e,:] ) + b
// mode 1: relu + bf16 output (feeds next GEMM); mode 0: fp32 output (feeds pooling)

__global__ __launch_bounds__(256) void k_agg(const uint2* __restrict__ tbf,
                                             const unsigned short* __restrict__ csr_row,
                                             const int* __restrict__ start,
                                             const int* __restrict__ endp,
                                             const float* __restrict__ dinv,
                                             const float* __restrict__ bias,
                                             float* __restrict__ hf,
                                             uint2* __restrict__ hb,
                                             int N, int mode) {
    int t = threadIdx.x;
    int v = blockIdx.x * 8 + (t >> 5);
    if (v >= N) return;
    int lane = t & 31;

    float a0, a1, a2, a3;
    {   // self loop term (table already scaled by dinv[v])
        uint2 sv = tbf[(size_t)v * 32 + lane];
        unpk2(sv.x, a0, a1); unpk2(sv.y, a2, a3);
    }

    int s = start[v], e = endp[v];
    int p = s;
    for (; p + 4 <= e; p += 4) {
        int r0 = csr_row[p], r1 = csr_row[p + 1], r2 = csr_row[p + 2], r3 = csr_row[p + 3];
        uint2 g0 = tbf[(size_t)r0 * 32 + lane];
        uint2 g1 = tbf[(size_t)r1 * 32 + lane];
        uint2 g2 = tbf[(size_t)r2 * 32 + lane];
        uint2 g3 = tbf[(size_t)r3 * 32 + lane];
        float f0, f1, f2, f3;
        unpk2(g0.x, f0, f1); unpk2(g0.y, f2, f3);
        a0 += f0; a1 += f1; a2 += f2; a3 += f3;
        unpk2(g1.x, f0, f1); unpk2(g1.y, f2, f3);
        a0 += f0; a1 += f1; a2 += f2; a3 += f3;
        unpk2(g2.x, f0, f1); unpk2(g2.y, f2, f3);
        a0 += f0; a1 += f1; a2 += f2; a3 += f3;
        unpk2(g3.x, f0, f1); unpk2(g3.y, f2, f3);
        a0 += f0; a1 += f1; a2 += f2; a3 += f3;
    }
    for (; p < e; ++p) {
        int r = csr_row[p];
        uint2 g = tbf[(size_t)r * 32 + lane];
        float f0, f1, f2, f3;
        unpk2(g.x, f0, f1); unpk2(g.y, f2, f3);
        a0 += f0; a1 += f1; a2 += f2; a3 += f3;
    }

    float dv = dinv[v];
    float4 b4 = *(const float4*)&bias[lane * 4];
    a0 = fmaf(a0, dv, b4.x); a1 = fmaf(a1, dv, b4.y);
    a2 = fmaf(a2, dv, b4.z); a3 = fmaf(a3, dv, b4.w);
    if (mode) {   // relu + bf16 pack
        a0 = fmaxf(a0, 0.f); a1 = fmaxf(a1, 0.f);
        a2 = fmaxf(a2, 0.f); a3 = fmaxf(a3, 0.f);
        uint2 o;
        o.x = pk2(a0, a1);
        o.y = pk2(a2, a3);
        hb[(size_t)v * 32 + lane] = o;
    } else {
        *(float4*)&hf[(size_t)v * FEAT + lane * 4] = make_float4(a0, a1, a2, a3);
    }
}

// ---------------- pooling (batch is sorted) + classifier ----------------

__global__ void k_gcnt(const int* __restrict__ batch, int* __restrict__ gcnt, int N) {
    int v = blockIdx.x * blockDim.x + threadIdx.x;
    if (v < N) atomicAdd(&gcnt[batch[v]], 1);
}

__global__ void k_goff(const int* __restrict__ gcnt, int* __restrict__ goff,
                       float* __restrict__ cntf) {
    __shared__ int s[NGRAPH];
    int t = threadIdx.x;
    int v = gcnt[t];
    s[t] = v;
    __syncthreads();
    for (int off = 1; off < NGRAPH; off <<= 1) {
        int u = (t >= off) ? s[t - off] : 0;
        __syncthreads();
        s[t] += u;
        __syncthreads();
    }
    goff[t] = s[t] - v;   // exclusive
    cntf[t] = (float)v;
}

__global__ __launch_bounds__(128) void k_pool(const float* __restrict__ h,
                                              const int* __restrict__ goff,
                                              const int* __restrict__ gcnt,
                                              float* __restrict__ pooled) {
    int g = blockIdx.x, t = threadIdx.x;
    int s = goff[g], n = gcnt[g];
    float acc = 0.f;
    for (int i = 0; i < n; ++i) acc += h[(size_t)(s + i) * FEAT + t];
    pooled[g * FEAT + t] = acc / fmaxf((float)n, 1.f);
}

__global__ void k_final(const float* __restrict__ pooled,
                        const float* __restrict__ linW, const float* __restrict__ linb,
                        float* __restrict__ out) {
    int idx = blockIdx.x * blockDim.x + threadIdx.x;
    if (idx >= NGRAPH * NCLS) return;
    int g = idx >> 4, c = idx & 15;
    float acc = 0.f;
    #pragma unroll 8
    for (int jj = 0; jj < FEAT; ++jj)
        acc = fmaf(pooled[g * FEAT + jj], linW[jj * NCLS + c], acc);
    out[idx] = acc + linb[c];
}

// ---------------- launch ----------------

extern "C" void kernel_launch(void* const* d_in, const int* in_sizes, int n_in,
                              void* d_out, int out_size, void* d_ws, size_t ws_size,
                              hipStream_t stream) {
    const float* x    = (const float*)d_in[0];
    const int*   ei   = (const int*)d_in[1];
    const int*   batch= (const int*)d_in[2];
    const float* W1   = (const float*)d_in[3];
    const float* b1   = (const float*)d_in[4];
    const float* W2   = (const float*)d_in[5];
    const float* b2   = (const float*)d_in[6];
    const float* W3   = (const float*)d_in[7];
    const float* b3   = (const float*)d_in[8];
    const float* linW = (const float*)d_in[9];
    const float* linb = (const float*)d_in[10];
    float* out = (float*)d_out;

    const int N = in_sizes[0] / FEAT;
    const int E = in_sizes[1] / 2;
    const int* row = ei;
    const int* col = ei + E;

    char* p = (char*)d_ws;
    auto alloc = [&](size_t bytes) { void* r = (void*)p; p += (bytes + 255) & ~(size_t)255; return r; };
    int*   hist    = (int*)  alloc((size_t)N * 4);
    int*   start   = (int*)  alloc((size_t)N * 4);
    int*   cur     = (int*)  alloc((size_t)N * 4);
    float* dinv    = (float*)alloc((size_t)N * 4);
    unsigned short* csr_row = (unsigned short*)alloc((size_t)E * 2);
    int*   partial = (int*)  alloc(4096);
    unsigned short* tbf = (unsigned short*)alloc((size_t)N * FEAT * 2); // bf16 [N,128], pre-scaled
    unsigned short* hbb = (unsigned short*)alloc((size_t)N * FEAT * 2); // bf16 h (layers 1-2)
    float* h       = (float*)alloc((size_t)N * FEAT * 4);               // fp32 h (layer 3)
    bf16x8* whi    = (bf16x8*)alloc(3 * 2048 * sizeof(bf16x8));
    bf16x8* wlo    = (bf16x8*)alloc(3 * 2048 * sizeof(bf16x8));
    float* pooled  = (float*)alloc((size_t)NGRAPH * FEAT * 4);
    float* cntf    = (float*)alloc((size_t)NGRAPH * 4);
    int*   gcnt    = (int*)  alloc((size_t)NGRAPH * 4);
    int*   goff    = (int*)  alloc((size_t)NGRAPH * 4);

    hipMemsetAsync(hist, 0, (size_t)N * 4, stream);
    hipMemsetAsync(gcnt, 0, (size_t)NGRAPH * 4, stream);

    const int nscan = (N + 255) / 256;

    k_hist  <<<(E + 255) / 256, 256, 0, stream>>>(col, hist, E);
    k_dinv  <<<nscan, 256, 0, stream>>>(hist, dinv, N);
    k_scanA <<<nscan, 256, 0, stream>>>(hist, partial, N);
    k_scanB <<<1, 256, 0, stream>>>(partial, nscan);
    k_scanC <<<nscan, 256, 0, stream>>>(hist, partial, start, cur, N);
    k_fill  <<<(E + 255) / 256, 256, 0, stream>>>(row, col, cur, csr_row, E);
    k_wsplit<<<24, 256, 0, stream>>>(W1, W2, W3, whi, wlo);
    k_gcnt  <<<nscan, 256, 0, stream>>>(batch, gcnt, N);
    k_goff  <<<1, NGRAPH, 0, stream>>>(gcnt, goff, cntf);

    const int gblk = (N + 63) / 64;
    const int ablk = (N + 7) / 8;

    k_gemm_f32 <<<gblk, 256, 0, stream>>>(x, whi, wlo, dinv, tbf, N);
    k_agg      <<<ablk, 256, 0, stream>>>((const uint2*)tbf, csr_row, start, cur, dinv, b1,
                                          nullptr, (uint2*)hbb, N, 1);
    k_gemm_bf16<<<gblk, 256, 0, stream>>>(hbb, whi + 2048, wlo + 2048, dinv, tbf, N);
    k_agg      <<<ablk, 256, 0, stream>>>((const uint2*)tbf, csr_row, start, cur, dinv, b2,
                                          nullptr, (uint2*)hbb, N, 1);
    k_gemm_bf16<<<gblk, 256, 0, stream>>>(hbb, whi + 4096, wlo + 4096, dinv, tbf, N);
    k_agg      <<<ablk, 256, 0, stream>>>((const uint2*)tbf, csr_row, start, cur, dinv, b3,
                                          h, nullptr, N, 0);

    k_pool <<<NGRAPH, 128, 0, stream>>>(h, goff, gcnt, pooled);
    k_final<<<(NGRAPH * NCLS + 255) / 256, 256, 0, stream>>>(pooled, linW, linb, out);
}